// Round 1
// baseline (330.616 us; speedup 1.0000x reference)
//
#include <hip/hip_runtime.h>

// o[i,u,j] = sum_{v<=u} t[v,j] * x[i,v,j]
// x: (b, n, d) fp32, t: (2n-2, d) fp32 (only first n rows used), o: (b, n, d) fp32
// d = 512 fixed; n, b derived from in_sizes.

typedef float f4 __attribute__((ext_vector_type(4)));

#define D  512
#define DV (D / 4)   // float4 lanes per row = 128

// Phase 1: per-chunk weighted sums. Grid: C*b blocks, DV threads.
__global__ __launch_bounds__(DV) void k_chunksum(
    const float* __restrict__ x, const float* __restrict__ t,
    float* __restrict__ S, int b, int n, int L) {
  const int c  = blockIdx.x / b;
  const int i  = blockIdx.x % b;
  const int jv = threadIdx.x;                 // float4 column index
  const size_t row0 = (size_t)c * L;
  const f4* xp = (const f4*)x + ((size_t)i * n + row0) * DV + jv;
  const f4* tp = (const f4*)t + row0 * DV + jv;
  f4 acc = {0.f, 0.f, 0.f, 0.f};
#pragma unroll 8
  for (int v = 0; v < L; ++v) {
    acc += xp[(size_t)v * DV] * tp[(size_t)v * DV];
  }
  ((f4*)S)[((size_t)c * b + i) * DV + jv] = acc;
}

// Phase 2: in-place exclusive scan of S along the chunk axis.
// One thread per (i, jv); b*DV threads total.
__global__ __launch_bounds__(256) void k_scan(float* __restrict__ S, int b, int C) {
  const int tid = blockIdx.x * 256 + threadIdx.x;
  if (tid >= b * DV) return;
  const int i  = tid / DV;
  const int jv = tid % DV;
  f4 run = {0.f, 0.f, 0.f, 0.f};
  for (int c = 0; c < C; ++c) {
    f4* p = (f4*)S + ((size_t)c * b + i) * DV + jv;
    f4 s = *p;
    *p = run;
    run += s;
  }
}

// Phase 3: local inclusive scan seeded with the chunk's exclusive prefix.
__global__ __launch_bounds__(DV) void k_out(
    const float* __restrict__ x, const float* __restrict__ t,
    const float* __restrict__ S, float* __restrict__ o, int b, int n, int L) {
  const int c  = blockIdx.x / b;
  const int i  = blockIdx.x % b;
  const int jv = threadIdx.x;
  const size_t row0  = (size_t)c * L;
  const size_t xbase = ((size_t)i * n + row0) * DV + jv;
  const f4* xp = (const f4*)x + xbase;
  const f4* tp = (const f4*)t + row0 * DV + jv;
  f4*       op = (f4*)o + xbase;
  f4 acc = ((const f4*)S)[((size_t)c * b + i) * DV + jv];
#pragma unroll 4
  for (int v = 0; v < L; ++v) {
    acc += xp[(size_t)v * DV] * tp[(size_t)v * DV];
    op[(size_t)v * DV] = acc;
  }
}

// Fallback (no workspace / non-divisible n): one thread per (i, jv), full scan.
__global__ __launch_bounds__(256) void k_naive(
    const float* __restrict__ x, const float* __restrict__ t,
    float* __restrict__ o, int b, int n) {
  const int tid = blockIdx.x * 256 + threadIdx.x;
  if (tid >= b * DV) return;
  const int i  = tid / DV;
  const int jv = tid % DV;
  const f4* xp = (const f4*)x + (size_t)i * n * DV + jv;
  const f4* tp = (const f4*)t + jv;
  f4*       op = (f4*)o + (size_t)i * n * DV + jv;
  f4 acc = {0.f, 0.f, 0.f, 0.f};
  for (int v = 0; v < n; ++v) {
    acc += xp[(size_t)v * DV] * tp[(size_t)v * DV];
    op[(size_t)v * DV] = acc;
  }
}

extern "C" void kernel_launch(void* const* d_in, const int* in_sizes, int n_in,
                              void* d_out, int out_size, void* d_ws, size_t ws_size,
                              hipStream_t stream) {
  const float* x = (const float*)d_in[0];
  const float* t = (const float*)d_in[1];
  float*       o = (float*)d_out;

  // t is (2n-2, d): n = (t_elems/d + 2) / 2 ; b = x_elems / (n*d)
  const long long t_elems = in_sizes[1];
  const int n = (int)((t_elems / D + 2) / 2);
  const int b = (int)((long long)in_sizes[0] / ((long long)n * D));

  const int C = 128;                       // chunks along the sequence
  const size_t need = (size_t)C * b * D * sizeof(float);

  if (n % C == 0 && ws_size >= need) {
    const int L = n / C;                   // 64 for n=8192
    float* S = (float*)d_ws;
    hipLaunchKernelGGL(k_chunksum, dim3(C * b), dim3(DV), 0, stream, x, t, S, b, n, L);
    const int scan_threads = b * DV;
    hipLaunchKernelGGL(k_scan, dim3((scan_threads + 255) / 256), dim3(256), 0, stream, S, b, C);
    hipLaunchKernelGGL(k_out, dim3(C * b), dim3(DV), 0, stream, x, t, S, o, b, n, L);
  } else {
    const int threads = b * DV;
    hipLaunchKernelGGL(k_naive, dim3((threads + 255) / 256), dim3(256), 0, stream, x, t, o, b, n);
  }
}

// Round 2
// 300.846 us; speedup vs baseline: 1.0990x; 1.0990x over previous
//
#include <hip/hip_runtime.h>

// o[i,u,j] = sum_{v<=u} t[v,j] * x[i,v,j]
// x: (b, n, d) fp32, t: (2n-2, d) fp32 (first n rows used), o: (b, n, d) fp32

typedef float f4 __attribute__((ext_vector_type(4)));

#define D  512
#define DV (D / 4)   // 128 float4 columns
#define C  128       // chunks along sequence
#define RS 4         // row-split factor in phase 1

// Phase 1: per-chunk weighted sums. Grid: C*b blocks, 512 threads.
// Threads: jv = tid & 127 (f4 column), h = tid >> 7 (row quarter).
__global__ __launch_bounds__(DV * RS) void k_chunksum(
    const float* __restrict__ x, const float* __restrict__ t,
    float* __restrict__ S, int b, int n, int L) {
  const int c  = blockIdx.x / b;
  const int i  = blockIdx.x % b;
  const int jv = threadIdx.x & (DV - 1);
  const int h  = threadIdx.x >> 7;
  const int rows = L / RS;                       // 16 for L=64
  const size_t row0 = (size_t)c * L + (size_t)h * rows;
  const f4* xp = (const f4*)x + ((size_t)i * n + row0) * DV + jv;
  const f4* tp = (const f4*)t + row0 * DV + jv;
  f4 acc = {0.f, 0.f, 0.f, 0.f};
#pragma unroll 8
  for (int v = 0; v < rows; ++v) {
    acc += xp[(size_t)v * DV] * tp[(size_t)v * DV];
  }
  __shared__ f4 red[RS][DV];                     // 8 KB
  red[h][jv] = acc;
  __syncthreads();
  if (h == 0) {
    f4 s = red[0][jv] + red[1][jv] + red[2][jv] + red[3][jv];
    ((f4*)S)[((size_t)c * b + i) * DV + jv] = s;
  }
}

// Phase 2 (fused lookback + local scan): each block redundantly reduces its
// exclusive prefix from S (cache-resident), then scans its chunk and writes o.
__global__ __launch_bounds__(DV) void k_out(
    const float* __restrict__ x, const float* __restrict__ t,
    const float* __restrict__ S, float* __restrict__ o, int b, int n, int L) {
  const int c  = blockIdx.x / b;
  const int i  = blockIdx.x % b;
  const int jv = threadIdx.x;

  // Exclusive-prefix lookback: sum S[c'][i][jv] for c' < c (independent loads).
  f4 acc = {0.f, 0.f, 0.f, 0.f};
  const f4* Sp = (const f4*)S + (size_t)i * DV + jv;
  const size_t cstride = (size_t)b * DV;
#pragma unroll 8
  for (int cp = 0; cp < c; ++cp) {
    acc += Sp[(size_t)cp * cstride];
  }

  const size_t row0  = (size_t)c * L;
  const size_t xbase = ((size_t)i * n + row0) * DV + jv;
  const f4* xp = (const f4*)x + xbase;
  const f4* tp = (const f4*)t + row0 * DV + jv;
  f4*       op = (f4*)o + xbase;
#pragma unroll 4
  for (int v = 0; v < L; ++v) {
    acc += xp[(size_t)v * DV] * tp[(size_t)v * DV];
    op[(size_t)v * DV] = acc;
  }
}

// Fallback: one thread per (i, jv), full sequential scan.
__global__ __launch_bounds__(256) void k_naive(
    const float* __restrict__ x, const float* __restrict__ t,
    float* __restrict__ o, int b, int n) {
  const int tid = blockIdx.x * 256 + threadIdx.x;
  if (tid >= b * DV) return;
  const int i  = tid / DV;
  const int jv = tid % DV;
  const f4* xp = (const f4*)x + (size_t)i * n * DV + jv;
  const f4* tp = (const f4*)t + jv;
  f4*       op = (f4*)o + (size_t)i * n * DV + jv;
  f4 acc = {0.f, 0.f, 0.f, 0.f};
  for (int v = 0; v < n; ++v) {
    acc += xp[(size_t)v * DV] * tp[(size_t)v * DV];
    op[(size_t)v * DV] = acc;
  }
}

extern "C" void kernel_launch(void* const* d_in, const int* in_sizes, int n_in,
                              void* d_out, int out_size, void* d_ws, size_t ws_size,
                              hipStream_t stream) {
  const float* x = (const float*)d_in[0];
  const float* t = (const float*)d_in[1];
  float*       o = (float*)d_out;

  const long long t_elems = in_sizes[1];
  const int n = (int)((t_elems / D + 2) / 2);
  const int b = (int)((long long)in_sizes[0] / ((long long)n * D));

  const size_t need = (size_t)C * b * D * sizeof(float);

  if (n % C == 0 && (n / C) % RS == 0 && ws_size >= need) {
    const int L = n / C;                         // 64 for n=8192
    float* S = (float*)d_ws;
    hipLaunchKernelGGL(k_chunksum, dim3(C * b), dim3(DV * RS), 0, stream,
                       x, t, S, b, n, L);
    hipLaunchKernelGGL(k_out, dim3(C * b), dim3(DV), 0, stream,
                       x, t, S, o, b, n, L);
  } else {
    const int threads = b * DV;
    hipLaunchKernelGGL(k_naive, dim3((threads + 255) / 256), dim3(256), 0, stream,
                       x, t, o, b, n);
  }
}